// Round 1
// baseline (1383.653 us; speedup 1.0000x reference)
//
#include <hip/hip_runtime.h>
#include <stdint.h>

// ============================================================================
// CTSimFBOnlyGLM — bit-exact replication of the JAX reference (XLA:CPU
// semantics) including the threefry2x32 PRNG chain.
//
// Active hypotheses this round (flip on failure):
//  H-RNG : jax_threefry_partitionable = True:
//            keys[t] = tf2x32((0,42),(0,t));  bits = o0^o1 of
//            tf2x32(keys[t],(0, b*64+r));  u = bitcast((bits>>9)|0x3f800000)-1
//  H-SP  : spatial projection: sequential-p  mul+add (no FMA; jaxlib = -mavx)
//  H-CONV: Eigen RowMajor gemv: 8-wide partials (mul+add), predux8 tree
//            ((a0+a4)+(a2+a6))+((a1+a5)+(a3+a7)), scalar tails k=248,249
//  H-FB  : feedback dot = sequential masked ascending-k sum (exact-gated 0/1)
//  H-SIG : logistic = 1/(1+exp(-x)); decided via margin ladder (fast sigmoid
//            +-2e-6 band -> double sigmoid +-5e-7 band -> Cephes f32 replica)
// ============================================================================

#pragma clang fp contract(off)

#define TF_ROUND(r) do { x0 += x1; x1 = (x1 << (r)) | (x1 >> (32 - (r))); x1 ^= x0; } while (0)

__device__ __forceinline__ void tf2x32(uint32_t k0, uint32_t k1,
                                       uint32_t x0, uint32_t x1,
                                       uint32_t& o0, uint32_t& o1) {
  const uint32_t k2 = k0 ^ k1 ^ 0x1BD11BDAu;
  x0 += k0; x1 += k1;
  TF_ROUND(13); TF_ROUND(15); TF_ROUND(26); TF_ROUND(6);
  x0 += k1; x1 += k2 + 1u;
  TF_ROUND(17); TF_ROUND(29); TF_ROUND(16); TF_ROUND(24);
  x0 += k2; x1 += k0 + 2u;
  TF_ROUND(13); TF_ROUND(15); TF_ROUND(26); TF_ROUND(6);
  x0 += k0; x1 += k1 + 3u;
  TF_ROUND(17); TF_ROUND(29); TF_ROUND(16); TF_ROUND(24);
  x0 += k1; x1 += k2 + 4u;
  TF_ROUND(13); TF_ROUND(15); TF_ROUND(26); TF_ROUND(6);
  x0 += k2; x1 += k0 + 5u;
  o0 = x0; o1 = x1;
}

// Cephes/Eigen-old-style f32 exp as XLA's GenerateVF32Exp emits it
// (separate mul/add roundings, no contraction).
__device__ __forceinline__ float xla_exp_f32(float x) {
  #pragma clang fp contract(off)
  x = fminf(x, 88.3762626647950f);
  x = fmaxf(x, -88.3762626647949f);
  float fx = x * 1.44269504088896341f + 0.5f;
  fx = floorf(fx);
  const float tmp = fx * 0.693359375f;
  const float z0  = fx * (-2.12194440e-4f);
  x = x - tmp;
  x = x - z0;
  const float zz = x * x;
  float y = 1.9875691500e-4f;
  y = y * x + 1.3981999507e-3f;
  y = y * x + 8.3334519073e-3f;
  y = y * x + 4.1665795894e-2f;
  y = y * x + 1.6666665459e-1f;
  y = y * x + 5.0000001201e-1f;
  y = y * zz + x;
  y = y + 1.0f;
  const int n = (int)fx;
  const float p2n = __uint_as_float((uint32_t)(n + 127) << 23);
  return y * p2n;
}

__device__ __forceinline__ float xla_sigmoid_f32(float x) {
  #pragma clang fp contract(off)
  const float e = xla_exp_f32(-x);
  return 1.0f / (1.0f + e);
}

// ---------------------------------------------------------------------------
// Kernel 1: sp[b,t] = sum_p w[p]*stim[b,p,t]   (sequential p, mul+add)
// 4096 threads, each computes 4 consecutive t via float4 loads.
// ---------------------------------------------------------------------------
__global__ __launch_bounds__(64) void k_sp(const float* __restrict__ stim,
                                           const float* __restrict__ w,
                                           float* __restrict__ sp) {
  #pragma clang fp contract(off)
  const int tid = blockIdx.x * 64 + threadIdx.x;   // 0..4095
  const int b = tid >> 10;                         // 1024 float4 per batch row
  const int q = tid & 1023;
  const float4* __restrict__ base = (const float4*)stim + (size_t)b * (2048u * 1024u) + q;
  float ax = 0.f, ay = 0.f, az = 0.f, aw = 0.f;
  #pragma unroll 16
  for (int p = 0; p < 2048; ++p) {
    const float4 v = base[(size_t)p * 1024];
    const float wp = w[p];
    ax = ax + wp * v.x;
    ay = ay + wp * v.y;
    az = az + wp * v.z;
    aw = aw + wp * v.w;
  }
  float4* o = (float4*)sp + b * 1024 + q;
  *o = make_float4(ax, ay, az, aw);
}

// ---------------------------------------------------------------------------
// Kernel 2: gensig[b,l] = conv_valid(sp, tc)[b,l] + bias
// Eigen RowMajor gemv model: 8 partials (mul+add), predux8 tree, 2 tails.
// ---------------------------------------------------------------------------
__global__ __launch_bounds__(64) void k_conv(const float* __restrict__ sp,
                                             const float* __restrict__ tc,
                                             const float* __restrict__ bias,
                                             float* __restrict__ gensig) {
  #pragma clang fp contract(off)
  const int tid = blockIdx.x * 64 + threadIdx.x;
  if (tid >= 4 * 3847) return;
  const int b = tid / 3847;
  const int l = tid - b * 3847;
  const float* __restrict__ s = sp + b * 4096 + l;
  float a[8];
  #pragma unroll
  for (int j = 0; j < 8; ++j) a[j] = 0.f;
  for (int c = 0; c < 31; ++c) {
    const int k = c * 8;
    #pragma unroll
    for (int j = 0; j < 8; ++j) a[j] = a[j] + s[k + j] * tc[k + j];
  }
  const float b0 = a[0] + a[4];
  const float b1 = a[1] + a[5];
  const float b2 = a[2] + a[6];
  const float b3 = a[3] + a[7];
  float cc = (b0 + b2) + (b1 + b3);
  cc = cc + s[248] * tc[248];
  cc = cc + s[249] * tc[249];
  gensig[tid] = cc + bias[0];
}

// ---------------------------------------------------------------------------
// Kernel 3: the sequential simulation. One wave (64 threads) per trajectory
// (b,r); 256 blocks. Feedback ring: ring[s] holds the partial feedback sum
// (k = 0..247 terms, chronological = ascending-k order) for future step
// s mod 256. k=248,249 tails come from registers sp2/sp1 (last two spikes).
// RNG computed per-lane, one step per lane per 64-step chunk.
// ---------------------------------------------------------------------------
__global__ __launch_bounds__(64) void k_sim(const float* __restrict__ gensig,
                                            const float* __restrict__ init,
                                            const float* __restrict__ fbf,
                                            float* __restrict__ out) {
  #pragma clang fp contract(off)
  __shared__ float ring[256];
  __shared__ float f_lds[256];
  __shared__ float init_lds[256];
  const int lane = threadIdx.x;
  const int traj = blockIdx.x;        // b*64 + r, flat (4,64) index
  const int b = traj >> 6;

  for (int j = lane; j < 256; j += 64) {
    f_lds[j]    = (j < 250) ? fbf[j] : 0.f;
    init_lds[j] = (j < 250) ? init[b * 250 + j] : 0.f;
    ring[j] = 0.f;
  }
  __syncthreads();

  // Initial-window contributions: slot s gets sum_{k=0..min(247,249-s)}
  // init[s+k]*f[k], ascending k (exact-gated products).
  for (int s = lane; s < 250; s += 64) {
    float acc = 0.f;
    int kmax = 249 - s; if (kmax > 247) kmax = 247;
    for (int k = 0; k <= kmax; ++k) acc = acc + init_lds[s + k] * f_lds[k];
    ring[s] = acc;
  }
  __syncthreads();

  const size_t ob = (size_t)traj * 4096;
  for (int j = lane; j < 250; j += 64) out[ob + j] = init_lds[j];

  const float f248 = f_lds[248];
  const float f249 = f_lds[249];
  float sp1 = init_lds[249];   // spike at t-1 (surrogate: init tail)
  float sp2 = init_lds[248];   // spike at t-2
  const float* __restrict__ grow = gensig + b * 3847;

  float pref = ring[0];        // prefetched slot for the next step

  for (int tb = 0; tb < 3846; tb += 64) {
    const int n = (3846 - tb < 64) ? (3846 - tb) : 64;
    const int tl = tb + lane;
    float vg = 0.f, vu = 0.f;
    if (tl < 3846) {
      vg = grow[tl];
      uint32_t a0, a1, c0, c1;
      tf2x32(0u, 42u, 0u, (uint32_t)tl, a0, a1);        // keys[t] (fold-like split)
      tf2x32(a0, a1, 0u, (uint32_t)traj, c0, c1);       // per-step bits, elem m=traj
      const uint32_t bits = c0 ^ c1;                    // partitionable 32-bit merge
      vu = __uint_as_float((bits >> 9) | 0x3f800000u) - 1.0f;
    }
    float vspk = 0.f;
    for (int i = 0; i < n; ++i) {
      const int h = (tb + i) & 255;
      float fbv = pref;                    // ring[h], read one step early
      if (lane == 0) ring[h] = 0.f;        // retire slot for reuse at t+256
      pref = ring[(h + 1) & 255];          // safe: scatter only touches >= h+3
      fbv = fbv + sp2 * f248;              // tail k=248 (exact-gated)
      fbv = fbv + sp1 * f249;              // tail k=249
      const float g = __shfl(vg, i);
      const float u = __shfl(vu, i);
      const float x = g + fbv;
      float s;
      const float ef = __expf(-x);
      const float rf = __builtin_amdgcn_rcpf(1.0f + ef);
      const float dlt = u - rf;
      if (fabsf(dlt) > 2e-6f) {            // fast path, wave-uniform
        s = (dlt < 0.f) ? 1.f : 0.f;
      } else {
        const double sd = 1.0 / (1.0 + exp(-(double)x));
        const double dd = (double)u - sd;
        if (fabs(dd) > 5e-7) s = (dd < 0.0) ? 1.f : 0.f;
        else s = (u < xla_sigmoid_f32(x)) ? 1.f : 0.f;   // ~1 draw per run
      }
      vspk = (lane == i) ? s : vspk;
      if (s != 0.f) {
        // scatter: this spike contributes f[250-d] to future step t+d,
        // d = 3..250 (d=1,2 handled as register tails). Chronological
        // arrival == ascending-k accumulation order, bit-exact.
        const int base = (lane - h) & 255;
        #pragma unroll
        for (int j = 0; j < 4; ++j) {
          const int d = (base + 64 * j) & 255;
          if (d >= 3 && d <= 250) {
            const int slot = (lane + 64 * j) & 255;
            ring[slot] = ring[slot] + f_lds[250 - d];
          }
        }
      }
      sp2 = sp1;
      sp1 = s;
    }
    if (tl < 3846) out[ob + 250 + tl] = vspk;
  }
}

// ---------------------------------------------------------------------------
extern "C" void kernel_launch(void* const* d_in, const int* in_sizes, int n_in,
                              void* d_out, int out_size, void* d_ws, size_t ws_size,
                              hipStream_t stream) {
  (void)in_sizes; (void)n_in; (void)out_size; (void)ws_size;
  const float* stim = (const float*)d_in[0];   // (4,2048,4096)
  const float* init = (const float*)d_in[1];   // (4,250)
  const float* spat = (const float*)d_in[2];   // (2048)
  const float* tcf  = (const float*)d_in[3];   // (250)
  const float* fbf  = (const float*)d_in[4];   // (250)
  const float* bias = (const float*)d_in[5];   // (1)
  float* out = (float*)d_out;                  // (4,64,4096)
  float* sp     = (float*)d_ws;                // 16384 floats
  float* gensig = sp + 16384;                  // 15388 floats

  hipLaunchKernelGGL(k_sp,   dim3(64),  dim3(64), 0, stream, stim, spat, sp);
  hipLaunchKernelGGL(k_conv, dim3(241), dim3(64), 0, stream, sp, tcf, bias, gensig);
  hipLaunchKernelGGL(k_sim,  dim3(256), dim3(64), 0, stream, gensig, init, fbf, out);
}

// Round 2
// 793.819 us; speedup vs baseline: 1.7430x; 1.7430x over previous
//
#include <hip/hip_runtime.h>
#include <stdint.h>

// ============================================================================
// CTSimFBOnlyGLM — bit-exact replication of the JAX reference (XLA:CPU
// semantics) including the threefry2x32 PRNG chain.
//
// Validated in R1 (absmax 0.0):
//  H-RNG : jax_threefry_partitionable=True fold-in split + 32-bit xor merge
//  H-SP  : spatial projection = sequential-p mul+add (no FMA)
//  H-CONV: Eigen RowMajor gemv: 8 partials, predux8 tree, tails k=248,249
//  H-FB  : feedback dot = ascending-k chronological accumulation, exact-gated
//  H-SIG : margin ladder (fast sigmoid 2e-6 -> double 5e-7 -> Cephes f32)
//
// R2 changes (performance only, arithmetic bit-identical):
//  * k_sim: 256-slot feedback ring moved from LDS into registers
//    (lane L holds slots {L, L+64, L+128, L+192} of the current chunk,
//    rotated every 64 steps). Scatter = 4 predicated VALU adds; f-coefficients
//    gathered from LDS one step ahead. Spike decision computed per-lane
//    (lane i owns step tb+i), broadcast via v_readlane. d=1,2 tails folded
//    into the ring (same-wave program order keeps the d=1 add before the
//    next step's read; per-slot add order stays ascending-k == R1 order).
//  * k_sp: 16384 scalar threads (one output each), unroll 32.
// ============================================================================

#pragma clang fp contract(off)

#define TF_ROUND(r) do { x0 += x1; x1 = (x1 << (r)) | (x1 >> (32 - (r))); x1 ^= x0; } while (0)

__device__ __forceinline__ void tf2x32(uint32_t k0, uint32_t k1,
                                       uint32_t x0, uint32_t x1,
                                       uint32_t& o0, uint32_t& o1) {
  const uint32_t k2 = k0 ^ k1 ^ 0x1BD11BDAu;
  x0 += k0; x1 += k1;
  TF_ROUND(13); TF_ROUND(15); TF_ROUND(26); TF_ROUND(6);
  x0 += k1; x1 += k2 + 1u;
  TF_ROUND(17); TF_ROUND(29); TF_ROUND(16); TF_ROUND(24);
  x0 += k2; x1 += k0 + 2u;
  TF_ROUND(13); TF_ROUND(15); TF_ROUND(26); TF_ROUND(6);
  x0 += k0; x1 += k1 + 3u;
  TF_ROUND(17); TF_ROUND(29); TF_ROUND(16); TF_ROUND(24);
  x0 += k1; x1 += k2 + 4u;
  TF_ROUND(13); TF_ROUND(15); TF_ROUND(26); TF_ROUND(6);
  x0 += k2; x1 += k0 + 5u;
  o0 = x0; o1 = x1;
}

// Cephes/Eigen-style f32 exp as XLA's GenerateVF32Exp emits it.
__device__ __forceinline__ float xla_exp_f32(float x) {
  #pragma clang fp contract(off)
  x = fminf(x, 88.3762626647950f);
  x = fmaxf(x, -88.3762626647949f);
  float fx = x * 1.44269504088896341f + 0.5f;
  fx = floorf(fx);
  const float tmp = fx * 0.693359375f;
  const float z0  = fx * (-2.12194440e-4f);
  x = x - tmp;
  x = x - z0;
  const float zz = x * x;
  float y = 1.9875691500e-4f;
  y = y * x + 1.3981999507e-3f;
  y = y * x + 8.3334519073e-3f;
  y = y * x + 4.1665795894e-2f;
  y = y * x + 1.6666665459e-1f;
  y = y * x + 5.0000001201e-1f;
  y = y * zz + x;
  y = y + 1.0f;
  const int n = (int)fx;
  const float p2n = __uint_as_float((uint32_t)(n + 127) << 23);
  return y * p2n;
}

__device__ __forceinline__ float xla_sigmoid_f32(float x) {
  #pragma clang fp contract(off)
  const float e = xla_exp_f32(-x);
  return 1.0f / (1.0f + e);
}

// ---------------------------------------------------------------------------
// Kernel 1: sp[b,t] = sum_p w[p]*stim[b,p,t]   (sequential p, mul+add)
// 16384 threads, one output each; lanes->consecutive t (coalesced).
// ---------------------------------------------------------------------------
__global__ __launch_bounds__(64) void k_sp(const float* __restrict__ stim,
                                           const float* __restrict__ w,
                                           float* __restrict__ sp) {
  #pragma clang fp contract(off)
  const int tid = blockIdx.x * 64 + threadIdx.x;   // 0..16383
  const int b = tid >> 12;
  const int t = tid & 4095;
  const float* __restrict__ base = stim + (size_t)b * (2048u * 4096u) + t;
  float acc = 0.f;
  #pragma unroll 32
  for (int p = 0; p < 2048; ++p) {
    acc = acc + w[p] * base[(size_t)p * 4096];
  }
  sp[tid] = acc;
}

// ---------------------------------------------------------------------------
// Kernel 2: gensig[b,l] = conv_valid(sp, tc)[b,l] + bias
// Eigen RowMajor gemv model: 8 partials (mul+add), predux8 tree, 2 tails.
// ---------------------------------------------------------------------------
__global__ __launch_bounds__(64) void k_conv(const float* __restrict__ sp,
                                             const float* __restrict__ tc,
                                             const float* __restrict__ bias,
                                             float* __restrict__ gensig) {
  #pragma clang fp contract(off)
  const int tid = blockIdx.x * 64 + threadIdx.x;
  if (tid >= 4 * 3847) return;
  const int b = tid / 3847;
  const int l = tid - b * 3847;
  const float* __restrict__ s = sp + b * 4096 + l;
  float a[8];
  #pragma unroll
  for (int j = 0; j < 8; ++j) a[j] = 0.f;
  for (int c = 0; c < 31; ++c) {
    const int k = c * 8;
    #pragma unroll
    for (int j = 0; j < 8; ++j) a[j] = a[j] + s[k + j] * tc[k + j];
  }
  const float b0 = a[0] + a[4];
  const float b1 = a[1] + a[5];
  const float b2 = a[2] + a[6];
  const float b3 = a[3] + a[7];
  float cc = (b0 + b2) + (b1 + b3);
  cc = cc + s[248] * tc[248];
  cc = cc + s[249] * tc[249];
  gensig[tid] = cc + bias[0];
}

// ---------------------------------------------------------------------------
// Kernel 3: sequential simulation, one wave per trajectory, ring in VGPRs.
// Lane L's regs r0..r3 hold feedback partial sums for steps
// tb+L, tb+64+L, tb+128+L, tb+192+L (rotated each 64-step chunk).
// Per-slot accumulation is ascending-k (chronological spike order) and
// exact-gated (only spike==1 terms added) — bit-identical to the reference's
// sequential einsum. d in [1,250] all via ring (same-wave DS-free ordering).
// ---------------------------------------------------------------------------
__global__ __launch_bounds__(64) void k_sim(const float* __restrict__ gensig,
                                            const float* __restrict__ init,
                                            const float* __restrict__ fbf,
                                            float* __restrict__ out) {
  #pragma clang fp contract(off)
  __shared__ float ring[256];
  __shared__ float f_lds[256];
  __shared__ float init_lds[256];
  const int lane = threadIdx.x;
  const int traj = blockIdx.x;        // b*64 + r, flat (4,64) index
  const int b = traj >> 6;

  for (int j = lane; j < 256; j += 64) {
    f_lds[j]    = (j < 250) ? fbf[j] : 0.f;
    init_lds[j] = (j < 250) ? init[b * 250 + j] : 0.f;
    ring[j] = 0.f;
  }
  __syncthreads();

  // Initial-window contributions: slot s = sum_{k=0..249-s} init[s+k]*f[k],
  // ascending k, ungated products (matches reference sequential order).
  for (int s = lane; s < 250; s += 64) {
    float acc = 0.f;
    const int kmax = 249 - s;
    for (int k = 0; k <= kmax; ++k) acc = acc + init_lds[s + k] * f_lds[k];
    ring[s] = acc;
  }
  __syncthreads();

  const size_t ob = (size_t)traj * 4096;
  for (int j = lane; j < 250; j += 64) out[ob + j] = init_lds[j];

  // Ring into registers.
  float r0 = ring[lane];
  float r1 = ring[lane + 64];
  float r2 = ring[lane + 128];
  float r3 = ring[lane + 192];

  const float* __restrict__ grow = gensig + b * 3847;

  // Coefficients for step i: lane L needs f[250 - d_j], d_j = ((L-i)&63)+64j,
  // valid iff 1<=d_j<=250; out-of-range indices wrap into f_lds[250..255]==0.
  float cf0 = f_lds[(250 - lane) & 255];
  float cf1 = f_lds[186 - lane];
  float cf2 = f_lds[122 - lane];
  float cf3 = f_lds[(58 - lane) & 255];

  for (int tb = 0; tb < 3846; tb += 64) {
    const int n = (3846 - tb < 64) ? (3846 - tb) : 64;
    const int tl = tb + lane;
    float vg = 0.f, vu = 0.f;
    if (tl < 3846) {
      vg = grow[tl];
      uint32_t a0, a1, c0, c1;
      tf2x32(0u, 42u, 0u, (uint32_t)tl, a0, a1);        // keys[t] (fold-like split)
      tf2x32(a0, a1, 0u, (uint32_t)traj, c0, c1);       // per-step bits, elem m=traj
      const uint32_t bits = c0 ^ c1;
      vu = __uint_as_float((bits >> 9) | 0x3f800000u) - 1.0f;
    }
    float vspk = 0.f;
    for (int i = 0; i < n; ++i) {
      // prefetch next step's coefficients (off the critical path)
      const int nb = (lane - i - 1) & 63;
      const float nf0 = f_lds[(250 - nb) & 255];
      const float nf1 = f_lds[186 - nb];
      const float nf2 = f_lds[122 - nb];
      const float nf3 = f_lds[(58 - nb) & 255];

      // lane i owns step tb+i: its r0 is the complete feedback sum
      const float x = vg + r0;
      float s;
      const float ef = __expf(-x);
      const float rf = __builtin_amdgcn_rcpf(1.0f + ef);
      const float dlt = vu - rf;
      if (fabsf(dlt) > 2e-6f) {            // fast path
        s = (dlt < 0.f) ? 1.f : 0.f;
      } else {
        const double sd = 1.0 / (1.0 + exp(-(double)x));
        const double dd = (double)vu - sd;
        if (fabs(dd) > 5e-7) s = (dd < 0.0) ? 1.f : 0.f;
        else s = (vu < xla_sigmoid_f32(x)) ? 1.f : 0.f;   // ~1 draw per run
      }
      const uint32_t sb = (uint32_t)__builtin_amdgcn_readlane((int)__float_as_uint(s), i);
      if (lane == i) { vspk = s; r0 = 0.f; }   // retire slot for t+256 reuse
      if (sb != 0u) {
        // physical reg for cf_j is r_j (lane>=i) or r_{(j+1)&3} (lane<i)
        const bool lo = lane < i;
        const float a0 = lo ? cf3 : cf0;
        const float a1 = lo ? cf0 : cf1;
        const float a2 = lo ? cf1 : cf2;
        const float a3 = lo ? cf2 : cf3;
        r0 = r0 + a0;
        r1 = r1 + a1;
        r2 = r2 + a2;
        r3 = r3 + a3;
      }
      cf0 = nf0; cf1 = nf1; cf2 = nf2; cf3 = nf3;
    }
    if (tl < 3846) out[ob + 250 + tl] = vspk;
    // rotate ring registers for the next 64-step chunk
    const float tmp = r0; r0 = r1; r1 = r2; r2 = r3; r3 = tmp;
  }
}

// ---------------------------------------------------------------------------
extern "C" void kernel_launch(void* const* d_in, const int* in_sizes, int n_in,
                              void* d_out, int out_size, void* d_ws, size_t ws_size,
                              hipStream_t stream) {
  (void)in_sizes; (void)n_in; (void)out_size; (void)ws_size;
  const float* stim = (const float*)d_in[0];   // (4,2048,4096)
  const float* init = (const float*)d_in[1];   // (4,250)
  const float* spat = (const float*)d_in[2];   // (2048)
  const float* tcf  = (const float*)d_in[3];   // (250)
  const float* fbf  = (const float*)d_in[4];   // (250)
  const float* bias = (const float*)d_in[5];   // (1)
  float* out = (float*)d_out;                  // (4,64,4096)
  float* sp     = (float*)d_ws;                // 16384 floats
  float* gensig = sp + 16384;                  // 15388 floats

  hipLaunchKernelGGL(k_sp,   dim3(256), dim3(64), 0, stream, stim, spat, sp);
  hipLaunchKernelGGL(k_conv, dim3(241), dim3(64), 0, stream, sp, tcf, bias, gensig);
  hipLaunchKernelGGL(k_sim,  dim3(256), dim3(64), 0, stream, gensig, init, fbf, out);
}

// Round 3
// 527.995 us; speedup vs baseline: 2.6206x; 1.5035x over previous
//
#include <hip/hip_runtime.h>
#include <stdint.h>

// ============================================================================
// CTSimFBOnlyGLM — bit-exact replication of the JAX reference (XLA:CPU
// semantics) including the threefry2x32 PRNG chain.
//
// Validated R1/R2 (absmax 0.0): threefry-partitionable RNG; sequential-p
// spatial proj; Eigen predux8 conv; ascending-k gated feedback accumulation;
// sigmoid decision ladder (fast 2e-6 -> double 5e-7 -> Cephes f32 replica).
//
// R3 (perf only; decisions provably identical):
//  * k_sim serial chain: decision via precomputed logit threshold
//      u < sigmoid(x)  <=>  theta(u) < x,  theta = logit(u)
//    theta/band precomputed 64-wide per chunk (off critical path). Fast path
//    is a single compare dlt = (vg - theta) + r0 > 0, guarded by |dlt| <= band
//    -> exact R2 ladder (wave-uniform, ~2e-5/step). Band covers XLA-sigmoid
//    error in x-space (2e-6/(1-u) tail term) + all float roundings (3e-7
//    scale terms + 1.5e-5 flat), each with >=2x safety margin.
//  * Scatter: branchless r_j += sf*a_j (v_fma, sgpr sf in {0,1} => bit-exact
//    add), coefficients from 4x128 LDS table T with immediate ds offsets
//    (T mapping == R2's cf/lo rotation, re-derived term-by-term).
//  * Spike bookkeeping in a scalar 64-bit mask.
//  * k_sp: w staged in LDS; explicit 64-deep register double-buffer keeps
//    ~64 global loads in flight per wave.
// ============================================================================

#pragma clang fp contract(off)

#define TF_ROUND(r) do { x0 += x1; x1 = (x1 << (r)) | (x1 >> (32 - (r))); x1 ^= x0; } while (0)

__device__ __forceinline__ void tf2x32(uint32_t k0, uint32_t k1,
                                       uint32_t x0, uint32_t x1,
                                       uint32_t& o0, uint32_t& o1) {
  const uint32_t k2 = k0 ^ k1 ^ 0x1BD11BDAu;
  x0 += k0; x1 += k1;
  TF_ROUND(13); TF_ROUND(15); TF_ROUND(26); TF_ROUND(6);
  x0 += k1; x1 += k2 + 1u;
  TF_ROUND(17); TF_ROUND(29); TF_ROUND(16); TF_ROUND(24);
  x0 += k2; x1 += k0 + 2u;
  TF_ROUND(13); TF_ROUND(15); TF_ROUND(26); TF_ROUND(6);
  x0 += k0; x1 += k1 + 3u;
  TF_ROUND(17); TF_ROUND(29); TF_ROUND(16); TF_ROUND(24);
  x0 += k1; x1 += k2 + 4u;
  TF_ROUND(13); TF_ROUND(15); TF_ROUND(26); TF_ROUND(6);
  x0 += k2; x1 += k0 + 5u;
  o0 = x0; o1 = x1;
}

// Cephes/Eigen-style f32 exp as XLA's GenerateVF32Exp emits it.
__device__ __forceinline__ float xla_exp_f32(float x) {
  #pragma clang fp contract(off)
  x = fminf(x, 88.3762626647950f);
  x = fmaxf(x, -88.3762626647949f);
  float fx = x * 1.44269504088896341f + 0.5f;
  fx = floorf(fx);
  const float tmp = fx * 0.693359375f;
  const float z0  = fx * (-2.12194440e-4f);
  x = x - tmp;
  x = x - z0;
  const float zz = x * x;
  float y = 1.9875691500e-4f;
  y = y * x + 1.3981999507e-3f;
  y = y * x + 8.3334519073e-3f;
  y = y * x + 4.1665795894e-2f;
  y = y * x + 1.6666665459e-1f;
  y = y * x + 5.0000001201e-1f;
  y = y * zz + x;
  y = y + 1.0f;
  const int n = (int)fx;
  const float p2n = __uint_as_float((uint32_t)(n + 127) << 23);
  return y * p2n;
}

__device__ __forceinline__ float xla_sigmoid_f32(float x) {
  #pragma clang fp contract(off)
  const float e = xla_exp_f32(-x);
  return 1.0f / (1.0f + e);
}

__device__ __forceinline__ float rl_f(float v, int i) {
  return __uint_as_float((uint32_t)__builtin_amdgcn_readlane((int)__float_as_uint(v), i));
}

// ---------------------------------------------------------------------------
// Kernel 1: sp[b,t] = sum_p w[p]*stim[b,p,t]   (sequential p, mul+add).
// w staged in LDS (keeps vmcnt stream pure); 64-deep register double-buffer
// keeps ~64 global loads outstanding per wave while the serial acc chain runs.
// ---------------------------------------------------------------------------
__global__ __launch_bounds__(64) void k_sp(const float* __restrict__ stim,
                                           const float* __restrict__ w,
                                           float* __restrict__ sp) {
  #pragma clang fp contract(off)
  __shared__ float w_lds[2048];
  const int lane = threadIdx.x;
  const int tid = blockIdx.x * 64 + lane;
  const int b = tid >> 12;
  const int t = tid & 4095;
  for (int j = lane; j < 2048; j += 64) w_lds[j] = w[j];
  __syncthreads();
  const float* __restrict__ base = stim + (size_t)b * (2048u * 4096u) + t;
  float buf[64];
  #pragma unroll
  for (int k = 0; k < 64; ++k) buf[k] = base[(size_t)k * 4096];
  float acc = 0.f;
  for (int c = 0; c < 32; ++c) {
    float nxt[64];
    if (c < 31) {
      const int pb = (c + 1) * 64;
      #pragma unroll
      for (int k = 0; k < 64; ++k) nxt[k] = base[(size_t)(pb + k) * 4096];
    }
    const float* __restrict__ wl = &w_lds[c * 64];
    #pragma unroll
    for (int k = 0; k < 64; ++k) acc = acc + wl[k] * buf[k];
    if (c < 31) {
      #pragma unroll
      for (int k = 0; k < 64; ++k) buf[k] = nxt[k];
    }
  }
  sp[tid] = acc;
}

// ---------------------------------------------------------------------------
// Kernel 2: gensig[b,l] = conv_valid(sp, tc)[b,l] + bias
// Eigen RowMajor gemv model: 8 partials (mul+add), predux8 tree, 2 tails.
// ---------------------------------------------------------------------------
__global__ __launch_bounds__(64) void k_conv(const float* __restrict__ sp,
                                             const float* __restrict__ tc,
                                             const float* __restrict__ bias,
                                             float* __restrict__ gensig) {
  #pragma clang fp contract(off)
  const int tid = blockIdx.x * 64 + threadIdx.x;
  if (tid >= 4 * 3847) return;
  const int b = tid / 3847;
  const int l = tid - b * 3847;
  const float* __restrict__ s = sp + b * 4096 + l;
  float a[8];
  #pragma unroll
  for (int j = 0; j < 8; ++j) a[j] = 0.f;
  for (int c = 0; c < 31; ++c) {
    const int k = c * 8;
    #pragma unroll
    for (int j = 0; j < 8; ++j) a[j] = a[j] + s[k + j] * tc[k + j];
  }
  const float b0 = a[0] + a[4];
  const float b1 = a[1] + a[5];
  const float b2 = a[2] + a[6];
  const float b3 = a[3] + a[7];
  float cc = (b0 + b2) + (b1 + b3);
  cc = cc + s[248] * tc[248];
  cc = cc + s[249] * tc[249];
  gensig[tid] = cc + bias[0];
}

// ---------------------------------------------------------------------------
// Kernel 3: sequential simulation, one wave per trajectory, ring in VGPRs.
// Register r_j of lane L holds the feedback partial sum for step tb+64j+L
// (retired slots roll to +256; chunk-end rotation r0<-r1<-r2<-r3<-r0).
// Coefficient table T[j][idx], idx = 64 + i - L:
//   j=0: idx<64 -> f[186+idx], idx>=64 -> f[idx-70]   (retired-slot branch)
//   j>=1:        f[186-64j+idx]
// (out-of-range -> 0; matches R2's validated cf/lo mapping term-by-term).
// ---------------------------------------------------------------------------
__global__ __launch_bounds__(64) void k_sim(const float* __restrict__ gensig,
                                            const float* __restrict__ init,
                                            const float* __restrict__ fbf,
                                            float* __restrict__ out) {
  #pragma clang fp contract(off)
  __shared__ float ring[256];
  __shared__ float f_lds[256];
  __shared__ float init_lds[256];
  __shared__ float T[512];
  const int lane = threadIdx.x;
  const int traj = blockIdx.x;        // b*64 + r, flat (4,64) index
  const int b = traj >> 6;

  for (int j = lane; j < 256; j += 64) {
    f_lds[j]    = (j < 250) ? fbf[j] : 0.f;
    init_lds[j] = (j < 250) ? init[b * 250 + j] : 0.f;
    ring[j] = 0.f;
  }
  __syncthreads();

  // Coefficient tables.
  for (int idx = lane; idx < 512; idx += 64) {
    const int j = idx >> 7;
    const int e = (idx & 127) - 64;
    int src;
    if (j == 0) src = (e < 0) ? (250 + e) : (e - 6);
    else        src = 250 - 64 * j + e;
    T[idx] = (src >= 0 && src < 250) ? f_lds[src] : 0.f;
  }

  // Initial-window ring: slot s = sum_{k=0..249-s} init[s+k]*f[k], asc. k.
  for (int s = lane; s < 250; s += 64) {
    float acc = 0.f;
    const int kmax = 249 - s;
    for (int k = 0; k <= kmax; ++k) acc = acc + init_lds[s + k] * f_lds[k];
    ring[s] = acc;
  }
  __syncthreads();

  const size_t ob = (size_t)traj * 4096;
  for (int j = lane; j < 250; j += 64) out[ob + j] = init_lds[j];

  float r0 = ring[lane];
  float r1 = ring[lane + 64];
  float r2 = ring[lane + 128];
  float r3 = ring[lane + 192];

  const float* __restrict__ grow = gensig + b * 3847;
  const float* __restrict__ Tl = &T[64 - lane];

  for (int tb = 0; tb < 3904; tb += 64) {     // 61 chunks; last one padded
    const int tl = tb + lane;
    float vg = 0.f, vu = 0.f, vgt, band;
    if (tl < 3846) {
      vg = grow[tl];
      uint32_t a0, a1, c0, c1;
      tf2x32(0u, 42u, 0u, (uint32_t)tl, a0, a1);      // keys[t] (fold-like split)
      tf2x32(a0, a1, 0u, (uint32_t)traj, c0, c1);     // per-step bits, elem m=traj
      const uint32_t bits = c0 ^ c1;
      vu = __uint_as_float((bits >> 9) | 0x3f800000u) - 1.0f;
      // theta = logit(u); x-space threshold. u=0 -> -inf (always-spike) OK.
      const float om = 1.0f - vu;                     // exact (u has <=23 bits)
      const float th = __log2f(vu / om) * 0.69314718055994531f;
      vgt = vg - th;
      band = 1.5e-5f + 2e-6f / om
           + 3e-7f * (fabsf(th) + fabsf(vg) + fabsf(vgt));
    } else {
      vgt = -INFINITY;                                // padded step: never spikes
      band = -1.0f;                                   // and never goes slow
    }
    uint64_t smask = 0;
    #pragma unroll 4
    for (int i = 0; i < 64; ++i) {
      const float a0 = Tl[i];
      const float a1 = Tl[i + 128];
      const float a2 = Tl[i + 256];
      const float a3 = Tl[i + 384];
      const float dlt = vgt + r0;                     // lane i: x - theta
      const uint64_t m1 = __ballot(dlt > 0.0f);
      const uint64_t m2 = __ballot(fabsf(dlt) <= band);
      uint32_t spike = (uint32_t)(m1 >> i) & 1u;
      if (__builtin_expect((int)((m2 >> i) & 1ull), 0)) {
        // Exact reference ladder (R1/R2-validated), wave-uniform, ~2e-5/step.
        const float vg_i = rl_f(vg, i);
        const float r0_i = rl_f(r0, i);               // before retirement
        const float u_i  = rl_f(vu, i);
        const float x = vg_i + r0_i;                  // == reference fl(g + fb)
        float s;
        const float ef = __expf(-x);
        const float rf = __builtin_amdgcn_rcpf(1.0f + ef);
        const float d2 = u_i - rf;
        if (fabsf(d2) > 2e-6f) s = (d2 < 0.f) ? 1.f : 0.f;
        else {
          const double sd = 1.0 / (1.0 + exp(-(double)x));
          const double dd = (double)u_i - sd;
          if (fabs(dd) > 5e-7) s = (dd < 0.0) ? 1.f : 0.f;
          else s = (u_i < xla_sigmoid_f32(x)) ? 1.f : 0.f;
        }
        spike = (s != 0.f) ? 1u : 0u;
      }
      smask |= ((uint64_t)spike) << i;
      const float sf = spike ? 1.0f : 0.0f;           // scalar 0/1
      r0 = (lane == i) ? 0.0f : r0;                   // retire slot (-> t+256)
      // Gated scatter: sf in {0,1} => fma == plain add bit-exactly.
      r0 = __builtin_fmaf(sf, a0, r0);
      r1 = __builtin_fmaf(sf, a1, r1);
      r2 = __builtin_fmaf(sf, a2, r2);
      r3 = __builtin_fmaf(sf, a3, r3);
    }
    if (tl < 3846) out[ob + 250 + tl] = (float)((smask >> lane) & 1ull);
    // rotate ring registers for the next 64-step chunk
    const float tmp = r0; r0 = r1; r1 = r2; r2 = r3; r3 = tmp;
  }
}

// ---------------------------------------------------------------------------
extern "C" void kernel_launch(void* const* d_in, const int* in_sizes, int n_in,
                              void* d_out, int out_size, void* d_ws, size_t ws_size,
                              hipStream_t stream) {
  (void)in_sizes; (void)n_in; (void)out_size; (void)ws_size;
  const float* stim = (const float*)d_in[0];   // (4,2048,4096)
  const float* init = (const float*)d_in[1];   // (4,250)
  const float* spat = (const float*)d_in[2];   // (2048)
  const float* tcf  = (const float*)d_in[3];   // (250)
  const float* fbf  = (const float*)d_in[4];   // (250)
  const float* bias = (const float*)d_in[5];   // (1)
  float* out = (float*)d_out;                  // (4,64,4096)
  float* sp     = (float*)d_ws;                // 16384 floats
  float* gensig = sp + 16384;                  // 15388 floats

  hipLaunchKernelGGL(k_sp,   dim3(256), dim3(64), 0, stream, stim, spat, sp);
  hipLaunchKernelGGL(k_conv, dim3(241), dim3(64), 0, stream, sp, tcf, bias, gensig);
  hipLaunchKernelGGL(k_sim,  dim3(256), dim3(64), 0, stream, gensig, init, fbf, out);
}